// Round 1
// baseline (289.705 us; speedup 1.0000x reference)
//
#include <hip/hip_runtime.h>
#include <hip/hip_bf16.h>
#include <stdint.h>

// OuterProductMean: B=1, S=512, R=256, C_M=256, C_P=32, C_Z=128
#define S_DIM 512
#define R_DIM 256
#define CM 256
#define CP 32
#define CZ 128

typedef __attribute__((ext_vector_type(8))) short bf16x8;
typedef __attribute__((ext_vector_type(4))) float f32x4;
typedef unsigned int u32;

__device__ __forceinline__ float bf2f(unsigned short u) {
  union { u32 i; float f; } v; v.i = ((u32)u) << 16; return v.f;
}
__device__ __forceinline__ unsigned short f2bf(float f) {
  union { float f; u32 i; } v; v.f = f;
  u32 x = v.i;
  u32 r = (x + 0x7FFFu + ((x >> 16) & 1u)) >> 16;
  return (unsigned short)r;
}

__device__ __forceinline__ void gload_lds16(const unsigned short* g, unsigned short* l) {
  __builtin_amdgcn_global_load_lds((const __attribute__((address_space(1))) u32*)(g),
                                   (__attribute__((address_space(3))) u32*)(l), 16, 0, 0);
}

// ---------------- K0a: fold LN gain into Wa/Wb -> W' (bf16), Ka, Ca ----------------
__global__ void prep_kernel(const float* __restrict__ Wa, const float* __restrict__ ba,
                            const float* __restrict__ Wb, const float* __restrict__ bb,
                            const float* __restrict__ ln_g, const float* __restrict__ ln_b,
                            unsigned short* __restrict__ wp, float* __restrict__ Ka,
                            float* __restrict__ Ca) {
  int t = threadIdx.x;
  if (t < 64) {
    int o = t;
    const float* W = (o < 32) ? (Wa + o * CM) : (Wb + (o - 32) * CM);
    float ka = 0.f, ca = 0.f;
    for (int c = 0; c < CM; ++c) {
      float w = W[c];
      unsigned short b = f2bf(w * ln_g[c]);
      wp[o * CM + c] = b;
      ka += bf2f(b);
      ca += w * ln_b[c];
    }
    ca += (o < 32) ? ba[o] : bb[o - 32];
    Ka[o] = ka; Ca[o] = ca;
  }
}

// ---------------- K0b: Wo -> bf16 ----------------
__global__ void cast_wo_kernel(const float* __restrict__ Wo, unsigned short* __restrict__ Wo_bf) {
  int idx = blockIdx.x * blockDim.x + threadIdx.x;
  if (idx < CZ * CP * CP) Wo_bf[idx] = f2bf(Wo[idx]);
}

// ---------------- K0c: scale[i][j] = 1/(1e-3 + sum_s mask[s,i]*mask[s,j]) ----------------
__global__ void scale_kernel(const float* __restrict__ mask, float* __restrict__ scale) {
  int i = blockIdx.x, j = threadIdx.x;
  float sum = 0.f;
  for (int s = 0; s < S_DIM; ++s) {
    sum += mask[s * R_DIM + i] * mask[s * R_DIM + j];
  }
  scale[i * R_DIM + j] = 1.0f / (1e-3f + sum);
}

// ---------------- K1: fused LN + projections -> leftT/rightT bf16 [8192][512] ----------------
#define K1_ROWS 64
#define XPAD 264  // 256 + 8 bf16 pad (row = 528 B, 16B-multiple, breaks bank alignment)

__global__ __launch_bounds__(256) void
ln_proj_kernel(const float* __restrict__ M, const float* __restrict__ mask,
               const unsigned short* __restrict__ wp_g, const float* __restrict__ Ka_g,
               const float* __restrict__ Ca_g,
               unsigned short* __restrict__ leftT, unsigned short* __restrict__ rightT) {
  __shared__ unsigned short xt[K1_ROWS * XPAD];
  __shared__ unsigned short wp[64 * XPAD];
  __shared__ float smu[K1_ROWS], srs[K1_ROWS], smk[K1_ROWS];
  __shared__ float sKa[64], sCa[64];

  const int t = threadIdx.x;
  const int lane = t & 63;
  const int w = t >> 6;
  const int i = blockIdx.x;       // residue index
  const int s0 = blockIdx.y * K1_ROWS;

  // W' [64][256] -> LDS (vector 8-bf16 chunks)
  for (int idx = t; idx < 64 * CM / 8; idx += 256) {
    int row = (idx * 8) / CM;
    int col = (idx * 8) % CM;
    const uint4 v = *(const uint4*)(wp_g + row * CM + col);
    *(uint4*)(&wp[row * XPAD + col]) = v;
  }
  if (t < 64) { sKa[t] = Ka_g[t]; sCa[t] = Ca_g[t]; }

  // wave w handles rows 16w..16w+15: load f32 row, stats, bf16 -> LDS
  for (int r = 0; r < 16; ++r) {
    int row = w * 16 + r;
    int sg = s0 + row;
    const float4 x = *(const float4*)(M + ((size_t)sg * R_DIM + i) * CM + lane * 4);
    float sum = x.x + x.y + x.z + x.w;
    float ssq = x.x * x.x + x.y * x.y + x.z * x.z + x.w * x.w;
    #pragma unroll
    for (int m = 1; m < 64; m <<= 1) {
      sum += __shfl_xor(sum, m);
      ssq += __shfl_xor(ssq, m);
    }
    float mu = sum * (1.0f / CM);
    float var = ssq * (1.0f / CM) - mu * mu;
    float rs = rsqrtf(var + 1e-5f);
    if (lane == 0) {
      smu[row] = mu; srs[row] = rs;
      smk[row] = mask[(size_t)sg * R_DIM + i];
    }
    ushort4 xb;
    xb.x = f2bf(x.x); xb.y = f2bf(x.y); xb.z = f2bf(x.z); xb.w = f2bf(x.w);
    *(ushort4*)(&xt[row * XPAD + lane * 4]) = xb;
  }
  __syncthreads();

  // MFMA: A = W' (M=64 outputs, wave w owns o-tile 16w..16w+15), B^T = xt rows (N=64), K=256
  f32x4 acc[4] = {{0.f, 0.f, 0.f, 0.f}, {0.f, 0.f, 0.f, 0.f},
                  {0.f, 0.f, 0.f, 0.f}, {0.f, 0.f, 0.f, 0.f}};
  #pragma unroll
  for (int k = 0; k < 8; ++k) {
    const int c0 = k * 32 + ((lane >> 4) << 3);
    bf16x8 a = *(const bf16x8*)(&wp[(w * 16 + (lane & 15)) * XPAD + c0]);
    #pragma unroll
    for (int nt = 0; nt < 4; ++nt) {
      bf16x8 b = *(const bf16x8*)(&xt[(nt * 16 + (lane & 15)) * XPAD + c0]);
      acc[nt] = __builtin_amdgcn_mfma_f32_16x16x32_bf16(a, b, acc[nt], 0, 0, 0);
    }
  }

  // epilogue: v = (rs*(dot - mu*Ka) + Ca) * mask ; scatter to leftT/rightT (bf16)
  #pragma unroll
  for (int nt = 0; nt < 4; ++nt) {
    int srow = nt * 16 + (lane & 15);
    float mu = smu[srow], rs = srs[srow], mk = smk[srow];
    int sg = s0 + srow;
    #pragma unroll
    for (int r = 0; r < 4; ++r) {
      int o = w * 16 + ((lane >> 4) << 2) + r;
      float v = (rs * (acc[nt][r] - mu * sKa[o]) + sCa[o]) * mk;
      unsigned short bv = f2bf(v);
      if (o < 32) leftT[(size_t)(i * 32 + o) * S_DIM + sg] = bv;
      else        rightT[(size_t)(i * 32 + (o - 32)) * S_DIM + sg] = bv;
    }
  }
}

// ---------------- K2: big GEMM [8192 x 8192 x 512] + fused Wo projection ----------------
#define BM 128
#define BN 128
#define BK 32
#define OPAD 1032  // 1024 + 8 bf16 pad -> row 2064 B (16B-mult, 8-bank spread)

__global__ __launch_bounds__(256) void
opm_gemm_kernel(const unsigned short* __restrict__ leftT, const unsigned short* __restrict__ rightT,
                const unsigned short* __restrict__ Wo_bf, const float* __restrict__ bo,
                const float* __restrict__ scale, float* __restrict__ out) {
  __shared__ unsigned short Ab[BM * BK];
  __shared__ unsigned short Bb[BN * BK];
  __shared__ unsigned short Ob[16 * OPAD];

  const int t = threadIdx.x;
  const int lane = t & 63;
  const int w = t >> 6;
  const int wm = w >> 1, wn = w & 1;
  const int m0 = blockIdx.y * BM;
  const int n0 = blockIdx.x * BN;

  f32x4 acc[4][4];
  #pragma unroll
  for (int a = 0; a < 4; ++a)
    #pragma unroll
    for (int b = 0; b < 4; ++b) acc[a][b] = (f32x4){0.f, 0.f, 0.f, 0.f};

  const unsigned short* Asrc = leftT + (size_t)m0 * S_DIM;
  const unsigned short* Bsrc = rightT + (size_t)n0 * S_DIM;

  for (int kt = 0; kt < S_DIM / BK; ++kt) {
    const int kbase = kt * BK;
    // stage A,B tiles: 128 rows x 32 k bf16 each; chunk c -> row c/4, 16B part c%4
    #pragma unroll
    for (int p = 0; p < 2; ++p) {
      int c = t + p * 256;
      int row = c >> 2, part = c & 3;
      gload_lds16(Asrc + (size_t)row * S_DIM + kbase + part * 8, &Ab[c * 8]);
      gload_lds16(Bsrc + (size_t)row * S_DIM + kbase + part * 8, &Bb[c * 8]);
    }
    __syncthreads();

    bf16x8 af[4], bfr[4];
    #pragma unroll
    for (int x = 0; x < 4; ++x) {
      af[x]  = *(const bf16x8*)(&Ab[(wm * 64 + x * 16 + (lane & 15)) * BK + ((lane >> 4) << 3)]);
      bfr[x] = *(const bf16x8*)(&Bb[(wn * 64 + x * 16 + (lane & 15)) * BK + ((lane >> 4) << 3)]);
    }
    #pragma unroll
    for (int mi = 0; mi < 4; ++mi)
      #pragma unroll
      for (int ni = 0; ni < 4; ++ni)
        acc[mi][ni] = __builtin_amdgcn_mfma_f32_16x16x32_bf16(af[mi], bfr[ni], acc[mi][ni], 0, 0, 0);
    __syncthreads();
  }

  // ---- epilogue part 1: acc (O tile) -> LDS as bf16 [pair p = il*4+jl][de = d*32+e] ----
  #pragma unroll
  for (int mi = 0; mi < 4; ++mi) {
    int tm = wm * 64 + mi * 16 + ((lane >> 4) << 2);
    #pragma unroll
    for (int ni = 0; ni < 4; ++ni) {
      int tn = wn * 64 + ni * 16 + (lane & 15);
      int jl = tn >> 5, e = tn & 31;
      #pragma unroll
      for (int r = 0; r < 4; ++r) {
        int tmr = tm + r;
        int il = tmr >> 5, d = tmr & 31;
        Ob[(il * 4 + jl) * OPAD + d * 32 + e] = f2bf(acc[mi][ni][r]);
      }
    }
  }
  __syncthreads();

  // ---- epilogue part 2: Z[pair][z] = O[pair][:] . Wo[z][:]  (M=16, N=128, K=1024) ----
  f32x4 zacc[2] = {{0.f, 0.f, 0.f, 0.f}, {0.f, 0.f, 0.f, 0.f}};
  for (int kk = 0; kk < 32; ++kk) {
    bf16x8 a = *(const bf16x8*)(&Ob[(lane & 15) * OPAD + kk * 32 + ((lane >> 4) << 3)]);
    #pragma unroll
    for (int zt = 0; zt < 2; ++zt) {
      int z = (w * 2 + zt) * 16 + (lane & 15);
      bf16x8 b = *(const bf16x8*)(Wo_bf + (size_t)z * (CP * CP) + kk * 32 + ((lane >> 4) << 3));
      zacc[zt] = __builtin_amdgcn_mfma_f32_16x16x32_bf16(a, b, zacc[zt], 0, 0, 0);
    }
  }

  #pragma unroll
  for (int zt = 0; zt < 2; ++zt) {
    int z = (w * 2 + zt) * 16 + (lane & 15);
    float bz = bo[z];
    #pragma unroll
    for (int r = 0; r < 4; ++r) {
      int p = ((lane >> 4) << 2) + r;
      int ig = blockIdx.y * 4 + (p >> 2);
      int jg = blockIdx.x * 4 + (p & 3);
      float v = (zacc[zt][r] + bz) * scale[ig * R_DIM + jg];
      out[((size_t)ig * R_DIM + jg) * CZ + z] = v;
    }
  }
}

extern "C" void kernel_launch(void* const* d_in, const int* in_sizes, int n_in,
                              void* d_out, int out_size, void* d_ws, size_t ws_size,
                              hipStream_t stream) {
  const float* M     = (const float*)d_in[0];
  const float* Mmask = (const float*)d_in[1];
  // d_in[2] = Z_raw (unused by the reference math)
  const float* ln_g  = (const float*)d_in[3];
  const float* ln_b  = (const float*)d_in[4];
  const float* Wa    = (const float*)d_in[5];
  const float* ba    = (const float*)d_in[6];
  const float* Wb    = (const float*)d_in[7];
  const float* bb    = (const float*)d_in[8];
  const float* Wo    = (const float*)d_in[9];
  const float* bo    = (const float*)d_in[10];
  float* out = (float*)d_out;

  char* ws = (char*)d_ws;
  unsigned short* leftT  = (unsigned short*)(ws);                    // 8192*512*2 = 8388608
  unsigned short* rightT = (unsigned short*)(ws + 8388608);          // 8388608
  unsigned short* wp     = (unsigned short*)(ws + 16777216);         // 32768
  float*          Ka     = (float*)(ws + 16810240);                  // 256
  float*          Ca     = (float*)(ws + 16810496);                  // 256
  unsigned short* Wo_bf  = (unsigned short*)(ws + 16810752);         // 262144
  float*          scale  = (float*)(ws + 17072896);                  // 262144
  (void)ws_size; (void)in_sizes; (void)n_in; (void)out_size;

  hipLaunchKernelGGL(prep_kernel, dim3(1), dim3(64), 0, stream,
                     Wa, ba, Wb, bb, ln_g, ln_b, wp, Ka, Ca);
  hipLaunchKernelGGL(cast_wo_kernel, dim3(512), dim3(256), 0, stream, Wo, Wo_bf);
  hipLaunchKernelGGL(scale_kernel, dim3(R_DIM), dim3(R_DIM), 0, stream, Mmask, scale);
  hipLaunchKernelGGL(ln_proj_kernel, dim3(R_DIM, S_DIM / K1_ROWS), dim3(256), 0, stream,
                     M, Mmask, wp, Ka, Ca, leftT, rightT);
  hipLaunchKernelGGL(opm_gemm_kernel, dim3(R_DIM * CP / BN, R_DIM * CP / BM), dim3(256), 0, stream,
                     leftT, rightT, Wo_bf, bo, scale, out);
}

// Round 2
// 237.375 us; speedup vs baseline: 1.2205x; 1.2205x over previous
//
#include <hip/hip_runtime.h>
#include <hip/hip_bf16.h>
#include <stdint.h>

// OuterProductMean: B=1, S=512, R=256, C_M=256, C_P=32, C_Z=128
#define S_DIM 512
#define R_DIM 256
#define CM 256
#define CP 32
#define CZ 128

typedef __attribute__((ext_vector_type(8))) short bf16x8;
typedef __attribute__((ext_vector_type(4))) float f32x4;
typedef unsigned int u32;

__device__ __forceinline__ float bf2f(unsigned short u) {
  union { u32 i; float f; } v; v.i = ((u32)u) << 16; return v.f;
}
__device__ __forceinline__ unsigned short f2bf(float f) {
  union { float f; u32 i; } v; v.f = f;
  u32 x = v.i;
  u32 r = (x + 0x7FFFu + ((x >> 16) & 1u)) >> 16;
  return (unsigned short)r;
}

__device__ __forceinline__ void gload_lds16(const unsigned short* g, unsigned short* l) {
  __builtin_amdgcn_global_load_lds((const __attribute__((address_space(1))) u32*)(g),
                                   (__attribute__((address_space(3))) u32*)(l), 16, 0, 0);
}

// ---------------- K0a: fold LN gain into Wa/Wb -> W' (bf16), Ka, Ca ----------------
// grid(64) x block(256): block o handles one output row, thread c one channel.
__global__ void prep_kernel(const float* __restrict__ Wa, const float* __restrict__ ba,
                            const float* __restrict__ Wb, const float* __restrict__ bb,
                            const float* __restrict__ ln_g, const float* __restrict__ ln_b,
                            unsigned short* __restrict__ wp, float* __restrict__ Ka,
                            float* __restrict__ Ca) {
  __shared__ float ska[4], sca[4];
  const int o = blockIdx.x;
  const int c = threadIdx.x;
  const float* W = (o < 32) ? (Wa + o * CM) : (Wb + (o - 32) * CM);
  float wv = W[c];
  unsigned short bv = f2bf(wv * ln_g[c]);
  wp[o * CM + c] = bv;
  float ka = bf2f(bv);
  float ca = wv * ln_b[c];
  #pragma unroll
  for (int m = 1; m < 64; m <<= 1) {
    ka += __shfl_xor(ka, m);
    ca += __shfl_xor(ca, m);
  }
  if ((c & 63) == 0) { ska[c >> 6] = ka; sca[c >> 6] = ca; }
  __syncthreads();
  if (c == 0) {
    Ka[o] = ska[0] + ska[1] + ska[2] + ska[3];
    Ca[o] = sca[0] + sca[1] + sca[2] + sca[3] + ((o < 32) ? ba[o] : bb[o - 32]);
  }
}

// ---------------- K0b: Wo -> bf16 ----------------
__global__ void cast_wo_kernel(const float* __restrict__ Wo, unsigned short* __restrict__ Wo_bf) {
  int idx = blockIdx.x * blockDim.x + threadIdx.x;
  if (idx < CZ * CP * CP) Wo_bf[idx] = f2bf(Wo[idx]);
}

// ---------------- K0c: scale[i][j] = 1/(1e-3 + sum_s mask[s,i]*mask[s,j]) ----------------
__global__ void scale_kernel(const float* __restrict__ mask, float* __restrict__ scale) {
  int i = blockIdx.x, j = threadIdx.x;
  float sum = 0.f;
  for (int s = 0; s < S_DIM; ++s) {
    sum += mask[s * R_DIM + i] * mask[s * R_DIM + j];
  }
  scale[i * R_DIM + j] = 1.0f / (1e-3f + sum);
}

// ---------------- K1: fused LN + projections -> leftT/rightT bf16 [8192][512] ----------------
#define K1_ROWS 64
#define XPAD 264  // 256 + 8 bf16 pad (row = 528 B)

__global__ __launch_bounds__(256) void
ln_proj_kernel(const float* __restrict__ M, const float* __restrict__ mask,
               const unsigned short* __restrict__ wp_g, const float* __restrict__ Ka_g,
               const float* __restrict__ Ca_g,
               unsigned short* __restrict__ leftT, unsigned short* __restrict__ rightT) {
  __shared__ unsigned short xt[K1_ROWS * XPAD];
  __shared__ unsigned short wp[64 * XPAD];
  __shared__ float smu[K1_ROWS], srs[K1_ROWS], smk[K1_ROWS];
  __shared__ float sKa[64], sCa[64];

  const int t = threadIdx.x;
  const int lane = t & 63;
  const int w = t >> 6;
  const int lm = lane & 15;
  const int rr = lane >> 4;
  const int i = blockIdx.x;       // residue index
  const int s0 = blockIdx.y * K1_ROWS;

  // W' [64][256] -> LDS (vector 8-bf16 chunks)
  for (int idx = t; idx < 64 * CM / 8; idx += 256) {
    int row = idx >> 5;           // 32 chunks of 8 per row
    int col = (idx & 31) * 8;
    *(uint4*)(&wp[row * XPAD + col]) = *(const uint4*)(wp_g + row * CM + col);
  }
  if (t < 64) { sKa[t] = Ka_g[t]; sCa[t] = Ca_g[t]; }

  // each wave: 4 rows in parallel (quarter-wave per row), 4 iterations
  #pragma unroll
  for (int it = 0; it < 4; ++it) {
    const int row = w * 16 + it * 4 + rr;
    const int sg = s0 + row;
    const float* src = M + ((size_t)sg * R_DIM + i) * CM;
    float4 x[4];
    #pragma unroll
    for (int ch = 0; ch < 4; ++ch) x[ch] = *(const float4*)(src + ch * 64 + lm * 4);
    float sum = 0.f, ssq = 0.f;
    #pragma unroll
    for (int ch = 0; ch < 4; ++ch) {
      sum += x[ch].x + x[ch].y + x[ch].z + x[ch].w;
      ssq += x[ch].x * x[ch].x + x[ch].y * x[ch].y + x[ch].z * x[ch].z + x[ch].w * x[ch].w;
    }
    #pragma unroll
    for (int m = 1; m < 16; m <<= 1) {
      sum += __shfl_xor(sum, m);
      ssq += __shfl_xor(ssq, m);
    }
    float mu = sum * (1.0f / CM);
    float var = ssq * (1.0f / CM) - mu * mu;
    float rs = rsqrtf(var + 1e-5f);
    if (lm == 0) {
      smu[row] = mu; srs[row] = rs;
      smk[row] = mask[(size_t)sg * R_DIM + i];
    }
    #pragma unroll
    for (int ch = 0; ch < 4; ++ch) {
      ushort4 xb;
      xb.x = f2bf(x[ch].x); xb.y = f2bf(x[ch].y); xb.z = f2bf(x[ch].z); xb.w = f2bf(x[ch].w);
      *(ushort4*)(&xt[row * XPAD + ch * 64 + lm * 4]) = xb;
    }
  }
  __syncthreads();

  // MFMA: A = W' (M=64 outputs, wave w owns o-tile 16w..16w+15), B^T = xt rows (N=64), K=256
  f32x4 acc[4] = {{0.f, 0.f, 0.f, 0.f}, {0.f, 0.f, 0.f, 0.f},
                  {0.f, 0.f, 0.f, 0.f}, {0.f, 0.f, 0.f, 0.f}};
  #pragma unroll
  for (int k = 0; k < 8; ++k) {
    const int c0 = k * 32 + ((lane >> 4) << 3);
    bf16x8 a = *(const bf16x8*)(&wp[(w * 16 + (lane & 15)) * XPAD + c0]);
    #pragma unroll
    for (int nt = 0; nt < 4; ++nt) {
      bf16x8 b = *(const bf16x8*)(&xt[(nt * 16 + (lane & 15)) * XPAD + c0]);
      acc[nt] = __builtin_amdgcn_mfma_f32_16x16x32_bf16(a, b, acc[nt], 0, 0, 0);
    }
  }

  // epilogue: v = (rs*(dot - mu*Ka) + Ca) * mask ; scatter to leftT/rightT (bf16)
  #pragma unroll
  for (int nt = 0; nt < 4; ++nt) {
    int srow = nt * 16 + (lane & 15);
    float mu = smu[srow], rs = srs[srow], mk = smk[srow];
    int sg = s0 + srow;
    #pragma unroll
    for (int r = 0; r < 4; ++r) {
      int o = w * 16 + ((lane >> 4) << 2) + r;
      float v = (rs * (acc[nt][r] - mu * sKa[o]) + sCa[o]) * mk;
      unsigned short bv = f2bf(v);
      if (o < 32) leftT[(size_t)(i * 32 + o) * S_DIM + sg] = bv;
      else        rightT[(size_t)(i * 32 + (o - 32)) * S_DIM + sg] = bv;
    }
  }
}

// ---------------- K2: big GEMM [8192 x 8192 x 512] + fused Wo projection ----------------
#define BM 128
#define BN 128
#define BK 64
#define OPAD 1032  // 1024 + 8 bf16 pad -> row 2064 B

__global__ __launch_bounds__(256) void
opm_gemm_kernel(const unsigned short* __restrict__ leftT, const unsigned short* __restrict__ rightT,
                const unsigned short* __restrict__ Wo_bf, const float* __restrict__ bo,
                const float* __restrict__ scale, float* __restrict__ out) {
  // union: A[128][64] (16KB) + B[128][64] (16KB) in main loop; Ob[16][OPAD] (33KB) in epilogue
  __shared__ __align__(16) unsigned short smem[16 * OPAD];
  unsigned short* Ab = smem;
  unsigned short* Bb = smem + BM * BK;
  unsigned short* Ob = smem;

  const int t = threadIdx.x;
  const int lane = t & 63;
  const int lm = lane & 15, lq = lane >> 4;
  const int w = t >> 6;
  const int wm = w >> 1, wn = w & 1;
  const int m0 = blockIdx.y * BM;
  const int n0 = blockIdx.x * BN;

  f32x4 acc[4][4];
  #pragma unroll
  for (int a = 0; a < 4; ++a)
    #pragma unroll
    for (int b = 0; b < 4; ++b) acc[a][b] = (f32x4){0.f, 0.f, 0.f, 0.f};

  const unsigned short* Asrc = leftT + (size_t)m0 * S_DIM;
  const unsigned short* Bsrc = rightT + (size_t)n0 * S_DIM;

  // staging chunk params: chunk c holds global 16B part p = (c&7) ^ ((c>>3)&7) of row c>>3
  // (linear LDS dest for global_load_lds; swizzle realized by permuting the SOURCE)
  int sc_r[4], sc_off[4];
  #pragma unroll
  for (int q = 0; q < 4; ++q) {
    int c = q * 256 + t;
    int r = c >> 3, s = c & 7;
    int p = s ^ (r & 7);
    sc_r[q] = r;
    sc_off[q] = p * 8;
  }

  for (int kt = 0; kt < S_DIM / BK; ++kt) {
    const int kbase = kt * BK;
    #pragma unroll
    for (int q = 0; q < 4; ++q) {
      int c = q * 256 + t;
      gload_lds16(Asrc + (size_t)sc_r[q] * S_DIM + kbase + sc_off[q], &Ab[c * 8]);
      gload_lds16(Bsrc + (size_t)sc_r[q] * S_DIM + kbase + sc_off[q], &Bb[c * 8]);
    }
    __syncthreads();

    #pragma unroll
    for (int ks = 0; ks < 2; ++ks) {
      bf16x8 af[4], bfr[4];
      const int kp = ks * 4 + lq;
      #pragma unroll
      for (int x = 0; x < 4; ++x) {
        const int rA = wm * 64 + x * 16 + lm;
        const int rB = wn * 64 + x * 16 + lm;
        af[x]  = *(const bf16x8*)(&Ab[rA * BK + ((kp ^ (rA & 7)) << 3)]);
        bfr[x] = *(const bf16x8*)(&Bb[rB * BK + ((kp ^ (rB & 7)) << 3)]);
      }
      #pragma unroll
      for (int mi = 0; mi < 4; ++mi)
        #pragma unroll
        for (int ni = 0; ni < 4; ++ni)
          acc[mi][ni] = __builtin_amdgcn_mfma_f32_16x16x32_bf16(af[mi], bfr[ni], acc[mi][ni], 0, 0, 0);
    }
    __syncthreads();
  }

  // ---- epilogue part 1: acc (O tile) -> LDS as bf16 [pair p = il*4+jl][de = d*32+e] ----
  // (Ob aliases Ab/Bb; last __syncthreads() above guarantees all reads done)
  #pragma unroll
  for (int mi = 0; mi < 4; ++mi) {
    int tm = wm * 64 + mi * 16 + (lq << 2);
    #pragma unroll
    for (int ni = 0; ni < 4; ++ni) {
      int tn = wn * 64 + ni * 16 + lm;
      int jl = tn >> 5, e = tn & 31;
      #pragma unroll
      for (int r = 0; r < 4; ++r) {
        int tmr = tm + r;
        int il = tmr >> 5, d = tmr & 31;
        Ob[(il * 4 + jl) * OPAD + d * 32 + e] = f2bf(acc[mi][ni][r]);
      }
    }
  }
  __syncthreads();

  // ---- epilogue part 2: Z[pair][z] = O[pair][:] . Wo[z][:]  (M=16, N=128, K=1024) ----
  f32x4 zacc[2] = {{0.f, 0.f, 0.f, 0.f}, {0.f, 0.f, 0.f, 0.f}};
  for (int kk = 0; kk < 32; ++kk) {
    bf16x8 a = *(const bf16x8*)(&Ob[lm * OPAD + kk * 32 + (lq << 3)]);
    #pragma unroll
    for (int zt = 0; zt < 2; ++zt) {
      int z = (w * 2 + zt) * 16 + lm;
      bf16x8 b = *(const bf16x8*)(Wo_bf + (size_t)z * (CP * CP) + kk * 32 + (lq << 3));
      zacc[zt] = __builtin_amdgcn_mfma_f32_16x16x32_bf16(a, b, zacc[zt], 0, 0, 0);
    }
  }

  #pragma unroll
  for (int zt = 0; zt < 2; ++zt) {
    int z = (w * 2 + zt) * 16 + lm;
    float bz = bo[z];
    #pragma unroll
    for (int r = 0; r < 4; ++r) {
      int p = (lq << 2) + r;
      int ig = blockIdx.y * 4 + (p >> 2);
      int jg = blockIdx.x * 4 + (p & 3);
      float v = (zacc[zt][r] + bz) * scale[ig * R_DIM + jg];
      out[((size_t)ig * R_DIM + jg) * CZ + z] = v;
    }
  }
}

extern "C" void kernel_launch(void* const* d_in, const int* in_sizes, int n_in,
                              void* d_out, int out_size, void* d_ws, size_t ws_size,
                              hipStream_t stream) {
  const float* M     = (const float*)d_in[0];
  const float* Mmask = (const float*)d_in[1];
  // d_in[2] = Z_raw (unused by the reference math)
  const float* ln_g  = (const float*)d_in[3];
  const float* ln_b  = (const float*)d_in[4];
  const float* Wa    = (const float*)d_in[5];
  const float* ba    = (const float*)d_in[6];
  const float* Wb    = (const float*)d_in[7];
  const float* bb    = (const float*)d_in[8];
  const float* Wo    = (const float*)d_in[9];
  const float* bo    = (const float*)d_in[10];
  float* out = (float*)d_out;

  char* ws = (char*)d_ws;
  unsigned short* leftT  = (unsigned short*)(ws);                    // 8388608 B
  unsigned short* rightT = (unsigned short*)(ws + 8388608);          // 8388608 B
  unsigned short* wp     = (unsigned short*)(ws + 16777216);         // 32768 B
  float*          Ka     = (float*)(ws + 16810240);                  // 256 B
  float*          Ca     = (float*)(ws + 16810496);                  // 256 B
  unsigned short* Wo_bf  = (unsigned short*)(ws + 16810752);         // 262144 B
  float*          scale  = (float*)(ws + 17072896);                  // 262144 B
  (void)ws_size; (void)in_sizes; (void)n_in; (void)out_size;

  hipLaunchKernelGGL(prep_kernel, dim3(64), dim3(256), 0, stream,
                     Wa, ba, Wb, bb, ln_g, ln_b, wp, Ka, Ca);
  hipLaunchKernelGGL(cast_wo_kernel, dim3(512), dim3(256), 0, stream, Wo, Wo_bf);
  hipLaunchKernelGGL(scale_kernel, dim3(R_DIM), dim3(R_DIM), 0, stream, Mmask, scale);
  hipLaunchKernelGGL(ln_proj_kernel, dim3(R_DIM, S_DIM / K1_ROWS), dim3(256), 0, stream,
                     M, Mmask, wp, Ka, Ca, leftT, rightT);
  hipLaunchKernelGGL(opm_gemm_kernel, dim3(R_DIM * CP / BN, R_DIM * CP / BM), dim3(256), 0, stream,
                     leftT, rightT, Wo_bf, bo, scale, out);
}

// Round 3
// 212.597 us; speedup vs baseline: 1.3627x; 1.1165x over previous
//
#include <hip/hip_runtime.h>
#include <hip/hip_bf16.h>
#include <stdint.h>

// OuterProductMean: B=1, S=512, R=256, C_M=256, C_P=32, C_Z=128
#define S_DIM 512
#define R_DIM 256
#define CM 256
#define CP 32
#define CZ 128

typedef __attribute__((ext_vector_type(8))) short bf16x8;
typedef __attribute__((ext_vector_type(4))) float f32x4;
typedef unsigned int u32;

__device__ __forceinline__ float bf2f(unsigned short u) {
  union { u32 i; float f; } v; v.i = ((u32)u) << 16; return v.f;
}
__device__ __forceinline__ unsigned short f2bf(float f) {
  union { float f; u32 i; } v; v.f = f;
  u32 x = v.i;
  u32 r = (x + 0x7FFFu + ((x >> 16) & 1u)) >> 16;
  return (unsigned short)r;
}

__device__ __forceinline__ void gload_lds16(const unsigned short* g, unsigned short* l) {
  __builtin_amdgcn_global_load_lds((const __attribute__((address_space(1))) u32*)(g),
                                   (__attribute__((address_space(3))) u32*)(l), 16, 0, 0);
}

// ---------------- K0a: fold LN gain into Wa/Wb -> W' (bf16), Ka, Ca ----------------
__global__ void prep_kernel(const float* __restrict__ Wa, const float* __restrict__ ba,
                            const float* __restrict__ Wb, const float* __restrict__ bb,
                            const float* __restrict__ ln_g, const float* __restrict__ ln_b,
                            unsigned short* __restrict__ wp, float* __restrict__ Ka,
                            float* __restrict__ Ca) {
  __shared__ float ska[4], sca[4];
  const int o = blockIdx.x;
  const int c = threadIdx.x;
  const float* W = (o < 32) ? (Wa + o * CM) : (Wb + (o - 32) * CM);
  float wv = W[c];
  unsigned short bv = f2bf(wv * ln_g[c]);
  wp[o * CM + c] = bv;
  float ka = bf2f(bv);
  float ca = wv * ln_b[c];
  #pragma unroll
  for (int m = 1; m < 64; m <<= 1) {
    ka += __shfl_xor(ka, m);
    ca += __shfl_xor(ca, m);
  }
  if ((c & 63) == 0) { ska[c >> 6] = ka; sca[c >> 6] = ca; }
  __syncthreads();
  if (c == 0) {
    Ka[o] = ska[0] + ska[1] + ska[2] + ska[3];
    Ca[o] = sca[0] + sca[1] + sca[2] + sca[3] + ((o < 32) ? ba[o] : bb[o - 32]);
  }
}

// ---------------- K0b: Wo -> bf16 ----------------
__global__ void cast_wo_kernel(const float* __restrict__ Wo, unsigned short* __restrict__ Wo_bf) {
  int idx = blockIdx.x * blockDim.x + threadIdx.x;
  if (idx < CZ * CP * CP) Wo_bf[idx] = f2bf(Wo[idx]);
}

// ---------------- K0c: scale[i][j] = 1/(1e-3 + sum_s mask[s,i]*mask[s,j]) ----------------
__global__ void scale_kernel(const float* __restrict__ mask, float* __restrict__ scale) {
  int i = blockIdx.x, j = threadIdx.x;
  float sum = 0.f;
  for (int s = 0; s < S_DIM; ++s) {
    sum += mask[s * R_DIM + i] * mask[s * R_DIM + j];
  }
  scale[i * R_DIM + j] = 1.0f / (1e-3f + sum);
}

// ---------------- K1: fused LN + projections -> leftT/rightT bf16 [8192][512] ----------------
#define K1_ROWS 64
#define XPAD 264

__global__ __launch_bounds__(256) void
ln_proj_kernel(const float* __restrict__ M, const float* __restrict__ mask,
               const unsigned short* __restrict__ wp_g, const float* __restrict__ Ka_g,
               const float* __restrict__ Ca_g,
               unsigned short* __restrict__ leftT, unsigned short* __restrict__ rightT) {
  __shared__ unsigned short xt[K1_ROWS * XPAD];
  __shared__ unsigned short wp[64 * XPAD];
  __shared__ float smu[K1_ROWS], srs[K1_ROWS], smk[K1_ROWS];
  __shared__ float sKa[64], sCa[64];

  const int t = threadIdx.x;
  const int lane = t & 63;
  const int w = t >> 6;
  const int lm = lane & 15;
  const int rr = lane >> 4;
  const int i = blockIdx.x;
  const int s0 = blockIdx.y * K1_ROWS;

  for (int idx = t; idx < 64 * CM / 8; idx += 256) {
    int row = idx >> 5;
    int col = (idx & 31) * 8;
    *(uint4*)(&wp[row * XPAD + col]) = *(const uint4*)(wp_g + row * CM + col);
  }
  if (t < 64) { sKa[t] = Ka_g[t]; sCa[t] = Ca_g[t]; }

  #pragma unroll
  for (int it = 0; it < 4; ++it) {
    const int row = w * 16 + it * 4 + rr;
    const int sg = s0 + row;
    const float* src = M + ((size_t)sg * R_DIM + i) * CM;
    float4 x[4];
    #pragma unroll
    for (int ch = 0; ch < 4; ++ch) x[ch] = *(const float4*)(src + ch * 64 + lm * 4);
    float sum = 0.f, ssq = 0.f;
    #pragma unroll
    for (int ch = 0; ch < 4; ++ch) {
      sum += x[ch].x + x[ch].y + x[ch].z + x[ch].w;
      ssq += x[ch].x * x[ch].x + x[ch].y * x[ch].y + x[ch].z * x[ch].z + x[ch].w * x[ch].w;
    }
    #pragma unroll
    for (int m = 1; m < 16; m <<= 1) {
      sum += __shfl_xor(sum, m);
      ssq += __shfl_xor(ssq, m);
    }
    float mu = sum * (1.0f / CM);
    float var = ssq * (1.0f / CM) - mu * mu;
    float rs = rsqrtf(var + 1e-5f);
    if (lm == 0) {
      smu[row] = mu; srs[row] = rs;
      smk[row] = mask[(size_t)sg * R_DIM + i];
    }
    #pragma unroll
    for (int ch = 0; ch < 4; ++ch) {
      ushort4 xb;
      xb.x = f2bf(x[ch].x); xb.y = f2bf(x[ch].y); xb.z = f2bf(x[ch].z); xb.w = f2bf(x[ch].w);
      *(ushort4*)(&xt[row * XPAD + ch * 64 + lm * 4]) = xb;
    }
  }
  __syncthreads();

  f32x4 acc[4] = {{0.f, 0.f, 0.f, 0.f}, {0.f, 0.f, 0.f, 0.f},
                  {0.f, 0.f, 0.f, 0.f}, {0.f, 0.f, 0.f, 0.f}};
  #pragma unroll
  for (int k = 0; k < 8; ++k) {
    const int c0 = k * 32 + ((lane >> 4) << 3);
    bf16x8 a = *(const bf16x8*)(&wp[(w * 16 + (lane & 15)) * XPAD + c0]);
    #pragma unroll
    for (int nt = 0; nt < 4; ++nt) {
      bf16x8 b = *(const bf16x8*)(&xt[(nt * 16 + (lane & 15)) * XPAD + c0]);
      acc[nt] = __builtin_amdgcn_mfma_f32_16x16x32_bf16(a, b, acc[nt], 0, 0, 0);
    }
  }

  #pragma unroll
  for (int nt = 0; nt < 4; ++nt) {
    int srow = nt * 16 + (lane & 15);
    float mu = smu[srow], rs = srs[srow], mk = smk[srow];
    int sg = s0 + srow;
    #pragma unroll
    for (int r = 0; r < 4; ++r) {
      int o = w * 16 + ((lane >> 4) << 2) + r;
      float v = (rs * (acc[nt][r] - mu * sKa[o]) + sCa[o]) * mk;
      unsigned short bv = f2bf(v);
      if (o < 32) leftT[(size_t)(i * 32 + o) * S_DIM + sg] = bv;
      else        rightT[(size_t)(i * 32 + (o - 32)) * S_DIM + sg] = bv;
    }
  }
}

// ---------------- K2: 256x256-tile GEMM [8192 x 8192 x 512] + fused Wo projection ----------------
// 8 waves (2M x 4N), BK=32, double-buffered LDS (64KB), 1 barrier per K-tile,
// staging overlaps compute (T3 minimum-2-phase), XCD-swizzled grid (T1).
#define NT 16          // 512 / 32 K-tiles

__global__ __launch_bounds__(512, 2) void
opm_gemm_kernel(const unsigned short* __restrict__ leftT, const unsigned short* __restrict__ rightT,
                const unsigned short* __restrict__ Wo_bf, const float* __restrict__ bo,
                const float* __restrict__ scale, float* __restrict__ out) {
  // smem: buf b at b*16384: A [256][32] (8192 shorts), B at +8192. Total 65536 B.
  __shared__ __align__(16) unsigned short smem[32768];

  const int t = threadIdx.x;
  const int lane = t & 63;
  const int lm = lane & 15, lq = lane >> 4;
  const int w = t >> 6;            // 0..7
  const int wm = w >> 2, wn = w & 3;

  // XCD-aware swizzle: 1024 blocks, 8 XCDs, chunk 128 contiguous per XCD
  const int bid = blockIdx.x;
  const int swz = (bid & 7) * 128 + (bid >> 3);
  const int by = swz >> 5, bx = swz & 31;

  const unsigned short* Asrc = leftT + (size_t)(by * 256) * S_DIM;
  const unsigned short* Bsrc = rightT + (size_t)(bx * 256) * S_DIM;

  // staging: chunk c = q*512+t -> row c>>2, lds slot c&3, global part (c&3)^((c>>3)&3)
  int arow[2], aoff[2];
  #pragma unroll
  for (int q = 0; q < 2; ++q) {
    int c = q * 512 + t;
    arow[q] = c >> 2;
    aoff[q] = (((c & 3) ^ ((c >> 3) & 3))) * 8;
  }

  f32x4 acc[8][4];
  #pragma unroll
  for (int a = 0; a < 8; ++a)
    #pragma unroll
    for (int b = 0; b < 4; ++b) acc[a][b] = (f32x4){0.f, 0.f, 0.f, 0.f};

  // prologue: stage tile 0 into buf 0
  #pragma unroll
  for (int q = 0; q < 2; ++q) {
    int c = q * 512 + t;
    gload_lds16(Asrc + (size_t)arow[q] * S_DIM + aoff[q], &smem[c * 8]);
    gload_lds16(Bsrc + (size_t)arow[q] * S_DIM + aoff[q], &smem[8192 + c * 8]);
  }

  const int slot = (lq ^ ((lm >> 1) & 3)) * 8;
  const int abase = (wm * 128 + lm) * 32 + slot;
  const int bbase = (wn * 64 + lm) * 32 + slot;

  for (int kt = 0; kt < NT; ++kt) {
    __syncthreads();   // drains this wave's loads for tile kt (vmcnt 0) + all-wave visibility

    if (kt + 1 < NT) {
      const int nb = ((kt + 1) & 1) * 16384;
      const int kb = (kt + 1) * 32;
      #pragma unroll
      for (int q = 0; q < 2; ++q) {
        int c = q * 512 + t;
        gload_lds16(Asrc + (size_t)arow[q] * S_DIM + kb + aoff[q], &smem[nb + c * 8]);
        gload_lds16(Bsrc + (size_t)arow[q] * S_DIM + kb + aoff[q], &smem[nb + 8192 + c * 8]);
      }
    }

    const unsigned short* Ab = &smem[(kt & 1) * 16384];
    const unsigned short* Bb = Ab + 8192;
    bf16x8 af[8], bf[4];
    #pragma unroll
    for (int mi = 0; mi < 8; ++mi) af[mi] = *(const bf16x8*)(&Ab[abase + mi * 512]);
    #pragma unroll
    for (int ni = 0; ni < 4; ++ni) bf[ni] = *(const bf16x8*)(&Bb[bbase + ni * 512]);
    #pragma unroll
    for (int mi = 0; mi < 8; ++mi)
      #pragma unroll
      for (int ni = 0; ni < 4; ++ni)
        acc[mi][ni] = __builtin_amdgcn_mfma_f32_16x16x32_bf16(af[mi], bf[ni], acc[mi][ni], 0, 0, 0);
  }

  __syncthreads();   // main loop done; LDS reusable as Ob

  // ---- fused Wo projection, 2 chunks of 32 pairs (Ob = 32 x 1024 bf16 = 64KB) ----
  const int ib0 = by * 8, jb0 = bx * 8;
  #pragma unroll
  for (int c = 0; c < 2; ++c) {
    if (wm == c) {
      // this half's acc -> Ob, XOR-swizzled rows
      #pragma unroll
      for (int mi = 0; mi < 8; ++mi) {
        #pragma unroll
        for (int ni = 0; ni < 4; ++ni) {
          int n = wn * 64 + ni * 16 + lm;
          int jl = n >> 5, e = n & 31;
          #pragma unroll
          for (int r = 0; r < 4; ++r) {
            int m = mi * 16 + lq * 4 + r;       // local 0..127
            int pairL = (m >> 5) * 8 + jl;      // 0..31
            int d = m & 31;
            u32 byte = (u32)pairL * 2048 + ((((u32)(d * 32 + e)) * 2) ^ ((u32)(pairL & 7) << 4));
            *(unsigned short*)((char*)smem + byte) = f2bf(acc[mi][ni][r]);
          }
        }
      }
    }
    __syncthreads();

    // Z[pair][z] = O[pair][:] . Wo[z][:]  (M=32, N=128 split 8 waves, K=1024)
    f32x4 zacc[2] = {{0.f, 0.f, 0.f, 0.f}, {0.f, 0.f, 0.f, 0.f}};
    const unsigned short* wsrc = Wo_bf + (size_t)(w * 16 + lm) * (CP * CP) + lq * 8;
    for (int kk = 0; kk < 32; ++kk) {
      bf16x8 bw = *(const bf16x8*)(wsrc + kk * 32);
      #pragma unroll
      for (int mf = 0; mf < 2; ++mf) {
        int pairL = mf * 16 + lm;
        u32 byte = (u32)pairL * 2048 + (((u32)(kk * 64 + lq * 16)) ^ ((u32)(pairL & 7) << 4));
        bf16x8 a = *(const bf16x8*)((const char*)smem + byte);
        zacc[mf] = __builtin_amdgcn_mfma_f32_16x16x32_bf16(a, bw, zacc[mf], 0, 0, 0);
      }
    }

    const int z = w * 16 + lm;
    const float bz = bo[z];
    #pragma unroll
    for (int mf = 0; mf < 2; ++mf) {
      #pragma unroll
      for (int r = 0; r < 4; ++r) {
        int pair = c * 32 + mf * 16 + lq * 4 + r;
        int ig = ib0 + (pair >> 3), jg = jb0 + (pair & 7);
        float v = (zacc[mf][r] + bz) * scale[ig * R_DIM + jg];
        out[((size_t)ig * R_DIM + jg) * CZ + z] = v;
      }
    }
    __syncthreads();  // protect Ob before chunk 1 overwrites
  }
}

extern "C" void kernel_launch(void* const* d_in, const int* in_sizes, int n_in,
                              void* d_out, int out_size, void* d_ws, size_t ws_size,
                              hipStream_t stream) {
  const float* M     = (const float*)d_in[0];
  const float* Mmask = (const float*)d_in[1];
  const float* ln_g  = (const float*)d_in[3];
  const float* ln_b  = (const float*)d_in[4];
  const float* Wa    = (const float*)d_in[5];
  const float* ba    = (const float*)d_in[6];
  const float* Wb    = (const float*)d_in[7];
  const float* bb    = (const float*)d_in[8];
  const float* Wo    = (const float*)d_in[9];
  const float* bo    = (const float*)d_in[10];
  float* out = (float*)d_out;

  char* ws = (char*)d_ws;
  unsigned short* leftT  = (unsigned short*)(ws);
  unsigned short* rightT = (unsigned short*)(ws + 8388608);
  unsigned short* wp     = (unsigned short*)(ws + 16777216);
  float*          Ka     = (float*)(ws + 16810240);
  float*          Ca     = (float*)(ws + 16810496);
  unsigned short* Wo_bf  = (unsigned short*)(ws + 16810752);
  float*          scale  = (float*)(ws + 17072896);
  (void)ws_size; (void)in_sizes; (void)n_in; (void)out_size;

  hipLaunchKernelGGL(prep_kernel, dim3(64), dim3(256), 0, stream,
                     Wa, ba, Wb, bb, ln_g, ln_b, wp, Ka, Ca);
  hipLaunchKernelGGL(cast_wo_kernel, dim3(512), dim3(256), 0, stream, Wo, Wo_bf);
  hipLaunchKernelGGL(scale_kernel, dim3(R_DIM), dim3(R_DIM), 0, stream, Mmask, scale);
  hipLaunchKernelGGL(ln_proj_kernel, dim3(R_DIM, S_DIM / K1_ROWS), dim3(256), 0, stream,
                     M, Mmask, wp, Ka, Ca, leftT, rightT);
  hipLaunchKernelGGL(opm_gemm_kernel, dim3(32 * 32), dim3(512), 0, stream,
                     leftT, rightT, Wo_bf, bo, scale, out);
}

// Round 4
// 166.975 us; speedup vs baseline: 1.7350x; 1.2732x over previous
//
#include <hip/hip_runtime.h>
#include <hip/hip_bf16.h>
#include <stdint.h>

// OuterProductMean: B=1, S=512, R=256, C_M=256, C_P=32, C_Z=128
#define S_DIM 512
#define R_DIM 256
#define CM 256
#define CP 32
#define CZ 128

typedef __attribute__((ext_vector_type(8))) short bf16x8;
typedef __attribute__((ext_vector_type(4))) float f32x4;
typedef unsigned int u32;

__device__ __forceinline__ float bf2f(unsigned short u) {
  union { u32 i; float f; } v; v.i = ((u32)u) << 16; return v.f;
}
__device__ __forceinline__ unsigned short f2bf(float f) {
  union { float f; u32 i; } v; v.f = f;
  u32 x = v.i;
  u32 r = (x + 0x7FFFu + ((x >> 16) & 1u)) >> 16;
  return (unsigned short)r;
}

__device__ __forceinline__ void gload_lds16(const unsigned short* g, unsigned short* l) {
  __builtin_amdgcn_global_load_lds((const __attribute__((address_space(1))) u32*)(g),
                                   (__attribute__((address_space(3))) u32*)(l), 16, 0, 0);
}

__device__ __forceinline__ void wave_bar() {
  asm volatile("" ::: "memory");
  __builtin_amdgcn_s_barrier();
  asm volatile("" ::: "memory");
}

// ---------------- K0a: fold LN gain into Wa/Wb -> W' (bf16), Ka, Ca ----------------
__global__ void prep_kernel(const float* __restrict__ Wa, const float* __restrict__ ba,
                            const float* __restrict__ Wb, const float* __restrict__ bb,
                            const float* __restrict__ ln_g, const float* __restrict__ ln_b,
                            unsigned short* __restrict__ wp, float* __restrict__ Ka,
                            float* __restrict__ Ca) {
  __shared__ float ska[4], sca[4];
  const int o = blockIdx.x;
  const int c = threadIdx.x;
  const float* W = (o < 32) ? (Wa + o * CM) : (Wb + (o - 32) * CM);
  float wv = W[c];
  unsigned short bv = f2bf(wv * ln_g[c]);
  wp[o * CM + c] = bv;
  float ka = bf2f(bv);
  float ca = wv * ln_b[c];
  #pragma unroll
  for (int m = 1; m < 64; m <<= 1) {
    ka += __shfl_xor(ka, m);
    ca += __shfl_xor(ca, m);
  }
  if ((c & 63) == 0) { ska[c >> 6] = ka; sca[c >> 6] = ca; }
  __syncthreads();
  if (c == 0) {
    Ka[o] = ska[0] + ska[1] + ska[2] + ska[3];
    Ca[o] = sca[0] + sca[1] + sca[2] + sca[3] + ((o < 32) ? ba[o] : bb[o - 32]);
  }
}

// ---------------- K0b: Wo -> bf16 ----------------
__global__ void cast_wo_kernel(const float* __restrict__ Wo, unsigned short* __restrict__ Wo_bf) {
  int idx = blockIdx.x * blockDim.x + threadIdx.x;
  if (idx < CZ * CP * CP) Wo_bf[idx] = f2bf(Wo[idx]);
}

// ---------------- K0c: scale[i][j] = 1/(1e-3 + sum_s mask[s,i]*mask[s,j]) ----------------
__global__ void scale_kernel(const float* __restrict__ mask, float* __restrict__ scale) {
  int i = blockIdx.x, j = threadIdx.x;
  float sum = 0.f;
  for (int s = 0; s < S_DIM; ++s) {
    sum += mask[s * R_DIM + i] * mask[s * R_DIM + j];
  }
  scale[i * R_DIM + j] = 1.0f / (1e-3f + sum);
}

// ---------------- K1: fused LN + projections -> leftT/rightT bf16 [8192][512] ----------------
#define K1_ROWS 64
#define XPAD 264

__global__ __launch_bounds__(256) void
ln_proj_kernel(const float* __restrict__ M, const float* __restrict__ mask,
               const unsigned short* __restrict__ wp_g, const float* __restrict__ Ka_g,
               const float* __restrict__ Ca_g,
               unsigned short* __restrict__ leftT, unsigned short* __restrict__ rightT) {
  __shared__ unsigned short xt[K1_ROWS * XPAD];
  __shared__ unsigned short wp[64 * XPAD];
  __shared__ float smu[K1_ROWS], srs[K1_ROWS], smk[K1_ROWS];
  __shared__ float sKa[64], sCa[64];

  const int t = threadIdx.x;
  const int lane = t & 63;
  const int w = t >> 6;
  const int lm = lane & 15;
  const int rr = lane >> 4;
  const int i = blockIdx.x;
  const int s0 = blockIdx.y * K1_ROWS;

  for (int idx = t; idx < 64 * CM / 8; idx += 256) {
    int row = idx >> 5;
    int col = (idx & 31) * 8;
    *(uint4*)(&wp[row * XPAD + col]) = *(const uint4*)(wp_g + row * CM + col);
  }
  if (t < 64) { sKa[t] = Ka_g[t]; sCa[t] = Ca_g[t]; }

  #pragma unroll
  for (int it = 0; it < 4; ++it) {
    const int row = w * 16 + it * 4 + rr;
    const int sg = s0 + row;
    const float* src = M + ((size_t)sg * R_DIM + i) * CM;
    float4 x[4];
    #pragma unroll
    for (int ch = 0; ch < 4; ++ch) x[ch] = *(const float4*)(src + ch * 64 + lm * 4);
    float sum = 0.f, ssq = 0.f;
    #pragma unroll
    for (int ch = 0; ch < 4; ++ch) {
      sum += x[ch].x + x[ch].y + x[ch].z + x[ch].w;
      ssq += x[ch].x * x[ch].x + x[ch].y * x[ch].y + x[ch].z * x[ch].z + x[ch].w * x[ch].w;
    }
    #pragma unroll
    for (int m = 1; m < 16; m <<= 1) {
      sum += __shfl_xor(sum, m);
      ssq += __shfl_xor(ssq, m);
    }
    float mu = sum * (1.0f / CM);
    float var = ssq * (1.0f / CM) - mu * mu;
    float rs = rsqrtf(var + 1e-5f);
    if (lm == 0) {
      smu[row] = mu; srs[row] = rs;
      smk[row] = mask[(size_t)sg * R_DIM + i];
    }
    #pragma unroll
    for (int ch = 0; ch < 4; ++ch) {
      ushort4 xb;
      xb.x = f2bf(x[ch].x); xb.y = f2bf(x[ch].y); xb.z = f2bf(x[ch].z); xb.w = f2bf(x[ch].w);
      *(ushort4*)(&xt[row * XPAD + ch * 64 + lm * 4]) = xb;
    }
  }
  __syncthreads();

  f32x4 acc[4] = {{0.f, 0.f, 0.f, 0.f}, {0.f, 0.f, 0.f, 0.f},
                  {0.f, 0.f, 0.f, 0.f}, {0.f, 0.f, 0.f, 0.f}};
  #pragma unroll
  for (int k = 0; k < 8; ++k) {
    const int c0 = k * 32 + ((lane >> 4) << 3);
    bf16x8 a = *(const bf16x8*)(&wp[(w * 16 + (lane & 15)) * XPAD + c0]);
    #pragma unroll
    for (int nt = 0; nt < 4; ++nt) {
      bf16x8 b = *(const bf16x8*)(&xt[(nt * 16 + (lane & 15)) * XPAD + c0]);
      acc[nt] = __builtin_amdgcn_mfma_f32_16x16x32_bf16(a, b, acc[nt], 0, 0, 0);
    }
  }

  #pragma unroll
  for (int nt = 0; nt < 4; ++nt) {
    int srow = nt * 16 + (lane & 15);
    float mu = smu[srow], rs = srs[srow], mk = smk[srow];
    int sg = s0 + srow;
    #pragma unroll
    for (int r = 0; r < 4; ++r) {
      int o = w * 16 + ((lane >> 4) << 2) + r;
      float v = (rs * (acc[nt][r] - mu * sKa[o]) + sCa[o]) * mk;
      unsigned short bv = f2bf(v);
      if (o < 32) leftT[(size_t)(i * 32 + o) * S_DIM + sg] = bv;
      else        rightT[(size_t)(i * 32 + (o - 32)) * S_DIM + sg] = bv;
    }
  }
}

// ---------------- K2: 256x256 tile, BK=64, counted-vmcnt deep pipeline + fused Wo ----------------
// 8 waves (2M x 4N), 2-tile dbuf in 128KB dynamic LDS, raw s_barrier + vmcnt(8)
// (never drains in-loop), prefetch distance = 2 tiles, T2 source-side XOR swizzle,
// bx-major XCD chunks for L2 locality.
#define NT2 8   // 512 / 64 K-tiles

__global__ __launch_bounds__(512, 1) void
opm_gemm_kernel(const unsigned short* __restrict__ leftT, const unsigned short* __restrict__ rightT,
                const unsigned short* __restrict__ Wo_bf, const float* __restrict__ bo,
                const float* __restrict__ scale, float* __restrict__ out) {
  extern __shared__ unsigned short smem[];  // 65536 shorts = 128 KiB

  const int t = threadIdx.x;
  const int lane = t & 63;
  const int lm = lane & 15, lq = lane >> 4;
  const int sw = lm & 7;
  const int w = t >> 6;            // 0..7
  const int wm = w >> 2, wn = w & 3;

  // XCD chunk = 128 blocks; within chunk bx-major: A panel (1MB) L2-resident
  const int bid = blockIdx.x;
  const int xcd = bid & 7, local = bid >> 3;
  const int by = xcd * 4 + (local & 3);
  const int bx = local >> 2;

  const unsigned short* Asrc = leftT + (size_t)(by * 256) * S_DIM;
  const unsigned short* Bsrc = rightT + (size_t)(bx * 256) * S_DIM;

  // staging: chunk c = q*512+t -> LDS row c>>3, slot c&7; global slot (c&7)^((c>>3)&7)
  int sr[4], so[4];
  #pragma unroll
  for (int q = 0; q < 4; ++q) {
    int c = q * 512 + t;
    sr[q] = c >> 3;
    so[q] = ((c & 7) ^ ((c >> 3) & 7)) * 8;
  }

  f32x4 acc[8][4];
  #pragma unroll
  for (int a = 0; a < 8; ++a)
    #pragma unroll
    for (int b = 0; b < 4; ++b) acc[a][b] = (f32x4){0.f, 0.f, 0.f, 0.f};

  // STAGE(tile kt -> buffer buf): 8 gloads/thread (4 A + 4 B)
  auto STAGE = [&](int kt, int buf) {
    const int kb = kt * 64;
    unsigned short* ab = smem + buf * 32768;
    #pragma unroll
    for (int q = 0; q < 4; ++q) {
      int c = q * 512 + t;
      gload_lds16(Asrc + (size_t)sr[q] * S_DIM + kb + so[q], ab + c * 8);
      gload_lds16(Bsrc + (size_t)sr[q] * S_DIM + kb + so[q], ab + 16384 + c * 8);
    }
  };

  // prologue: fill both buffers
  STAGE(0, 0);
  STAGE(1, 1);

  #pragma unroll
  for (int kt = 0; kt < NT2; ++kt) {
    const int cur = kt & 1;
    // wait for tile kt's 8 loads (tile kt+1's 8 may stay in flight)
    if (kt < NT2 - 1) asm volatile("s_waitcnt vmcnt(8)" ::: "memory");
    else              asm volatile("s_waitcnt vmcnt(0)" ::: "memory");
    wave_bar();   // all waves' tile-kt loads landed -> buffer readable

    const unsigned short* Ab = smem + cur * 32768;
    const unsigned short* Bb = Ab + 16384;
    #pragma unroll
    for (int ks = 0; ks < 2; ++ks) {
      const int kp = ks * 4 + lq;
      const int slot = (kp ^ sw) << 3;
      bf16x8 af[8], bfr[4];
      #pragma unroll
      for (int mi = 0; mi < 8; ++mi)
        af[mi] = *(const bf16x8*)(&Ab[(wm * 128 + mi * 16 + lm) * 64 + slot]);
      #pragma unroll
      for (int ni = 0; ni < 4; ++ni)
        bfr[ni] = *(const bf16x8*)(&Bb[(wn * 64 + ni * 16 + lm) * 64 + slot]);
      #pragma unroll
      for (int mi = 0; mi < 8; ++mi)
        #pragma unroll
        for (int ni = 0; ni < 4; ++ni)
          acc[mi][ni] = __builtin_amdgcn_mfma_f32_16x16x32_bf16(af[mi], bfr[ni], acc[mi][ni], 0, 0, 0);
    }

    wave_bar();   // all waves done reading buffer `cur`
    if (kt + 2 < NT2) STAGE(kt + 2, cur);   // safe: everyone passed the read-barrier
  }

  // ---- epilogue part 1: acc -> Ob (64 pairs x 1024 de, XOR-swizzled rows, 128KB) ----
  #pragma unroll
  for (int mi = 0; mi < 8; ++mi) {
    #pragma unroll
    for (int ni = 0; ni < 4; ++ni) {
      const int n = wn * 64 + ni * 16 + lm;
      const int jl = n >> 5, e = n & 31;
      #pragma unroll
      for (int r = 0; r < 4; ++r) {
        const int m = wm * 128 + mi * 16 + lq * 4 + r;
        const int il = m >> 5, d = m & 31;
        const int pair = il * 8 + jl;
        u32 byte = (u32)pair * 2048 + ((((u32)(d * 32 + e)) * 2) ^ ((u32)(pair & 7) << 4));
        *(unsigned short*)((char*)smem + byte) = f2bf(acc[mi][ni][r]);
      }
    }
  }
  __syncthreads();

  // ---- epilogue part 2: Z[pair][z] = O[pair][:] . Wo[z][:]  (M=64, N=128/8waves, K=1024) ----
  f32x4 zacc[4] = {{0.f, 0.f, 0.f, 0.f}, {0.f, 0.f, 0.f, 0.f},
                   {0.f, 0.f, 0.f, 0.f}, {0.f, 0.f, 0.f, 0.f}};
  const unsigned short* wsrc = Wo_bf + (size_t)(w * 16 + lm) * (CP * CP) + lq * 8;
  #pragma unroll 4
  for (int kk = 0; kk < 32; ++kk) {
    bf16x8 bw = *(const bf16x8*)(wsrc + kk * 32);
    #pragma unroll
    for (int pt = 0; pt < 4; ++pt) {
      const int pairL = pt * 16 + lm;
      u32 byte = (u32)pairL * 2048 + (((u32)(kk * 64 + lq * 16)) ^ ((u32)(pairL & 7) << 4));
      bf16x8 a = *(const bf16x8*)((const char*)smem + byte);
      zacc[pt] = __builtin_amdgcn_mfma_f32_16x16x32_bf16(a, bw, zacc[pt], 0, 0, 0);
    }
  }

  const int z = w * 16 + lm;
  const float bz = bo[z];
  #pragma unroll
  for (int pt = 0; pt < 4; ++pt) {
    #pragma unroll
    for (int r = 0; r < 4; ++r) {
      const int pair = pt * 16 + lq * 4 + r;
      const int ig = by * 8 + (pair >> 3), jg = bx * 8 + (pair & 7);
      float v = (zacc[pt][r] + bz) * scale[ig * R_DIM + jg];
      out[((size_t)ig * R_DIM + jg) * CZ + z] = v;
    }
  }
}

extern "C" void kernel_launch(void* const* d_in, const int* in_sizes, int n_in,
                              void* d_out, int out_size, void* d_ws, size_t ws_size,
                              hipStream_t stream) {
  const float* M     = (const float*)d_in[0];
  const float* Mmask = (const float*)d_in[1];
  const float* ln_g  = (const float*)d_in[3];
  const float* ln_b  = (const float*)d_in[4];
  const float* Wa    = (const float*)d_in[5];
  const float* ba    = (const float*)d_in[6];
  const float* Wb    = (const float*)d_in[7];
  const float* bb    = (const float*)d_in[8];
  const float* Wo    = (const float*)d_in[9];
  const float* bo    = (const float*)d_in[10];
  float* out = (float*)d_out;

  char* ws = (char*)d_ws;
  unsigned short* leftT  = (unsigned short*)(ws);
  unsigned short* rightT = (unsigned short*)(ws + 8388608);
  unsigned short* wp     = (unsigned short*)(ws + 16777216);
  float*          Ka     = (float*)(ws + 16810240);
  float*          Ca     = (float*)(ws + 16810496);
  unsigned short* Wo_bf  = (unsigned short*)(ws + 16810752);
  float*          scale  = (float*)(ws + 17072896);
  (void)ws_size; (void)in_sizes; (void)n_in; (void)out_size;

  // allow 128KB dynamic LDS (deterministic, idempotent, host-side only)
  hipFuncSetAttribute((const void*)opm_gemm_kernel,
                      hipFuncAttributeMaxDynamicSharedMemorySize, 131072);

  hipLaunchKernelGGL(prep_kernel, dim3(64), dim3(256), 0, stream,
                     Wa, ba, Wb, bb, ln_g, ln_b, wp, Ka, Ca);
  hipLaunchKernelGGL(cast_wo_kernel, dim3(512), dim3(256), 0, stream, Wo, Wo_bf);
  hipLaunchKernelGGL(scale_kernel, dim3(R_DIM), dim3(R_DIM), 0, stream, Mmask, scale);
  hipLaunchKernelGGL(ln_proj_kernel, dim3(R_DIM, S_DIM / K1_ROWS), dim3(256), 0, stream,
                     M, Mmask, wp, Ka, Ca, leftT, rightT);
  hipLaunchKernelGGL(opm_gemm_kernel, dim3(1024), dim3(512), 131072, stream,
                     leftT, rightT, Wo_bf, bo, scale, out);
}